// Round 1
// baseline (1071.122 us; speedup 1.0000x reference)
//
#include <hip/hip_runtime.h>

#define NN 50000
#define NE 800000
#define FD 64
#define NG 256

__device__ __forceinline__ unsigned enc_f(float f) {
    unsigned u = __float_as_uint(f);
    return (u & 0x80000000u) ? ~u : (u | 0x80000000u);
}
__device__ __forceinline__ float dec_f(unsigned e) {
    unsigned u = (e & 0x80000000u) ? (e & 0x7FFFFFFFu) : ~e;
    return __uint_as_float(u);
}

// Fused x@{W0,W1,W2,W3}+b -> out[N][256] (cols 0-63:q, 64-127:k, 128-191:v, 192-255:s)
__global__ __launch_bounds__(256) void proj4(
    const float* __restrict__ X,
    const float* __restrict__ W0, const float* __restrict__ b0,
    const float* __restrict__ W1, const float* __restrict__ b1,
    const float* __restrict__ W2, const float* __restrict__ b2,
    const float* __restrict__ W3, const float* __restrict__ b3,
    float* __restrict__ out, int n)
{
    __shared__ float Xs[16][64];
    int r0 = blockIdx.x * 16;
    int tid = threadIdx.x;
    for (int i = tid; i < 16 * 64; i += 256) {
        int r = i >> 6, c = i & 63;
        int gr = r0 + r;
        Xs[r][c] = (gr < n) ? X[gr * 64 + c] : 0.f;
    }
    __syncthreads();
    int c = tid & 63;
    int m = tid >> 6;
    const float* W = (m == 0) ? W0 : (m == 1) ? W1 : (m == 2) ? W2 : W3;
    const float* B = (m == 0) ? b0 : (m == 1) ? b1 : (m == 2) ? b2 : b3;
    float bias = B[c];
    float acc[16];
#pragma unroll
    for (int r = 0; r < 16; r++) acc[r] = bias;
    for (int k = 0; k < 64; k++) {
        float w = W[k * 64 + c];
#pragma unroll
        for (int r = 0; r < 16; r++) acc[r] += Xs[r][k] * w;
    }
    for (int r = 0; r < 16; r++) {
        int gr = r0 + r;
        if (gr < n) out[gr * 256 + tid] = acc[r];
    }
}

// One wave per edge: logit = dot(q[dst], k[src]+ew*We)/8; segment-max via atomicMax(enc)
__global__ __launch_bounds__(256) void edge_logits(
    const int* __restrict__ ei, const float* __restrict__ ew,
    const float* __restrict__ We, const float* __restrict__ QKVS,
    float* __restrict__ L, unsigned* __restrict__ Menc, int nE)
{
    int wid = (int)((blockIdx.x * 256u + threadIdx.x) >> 6);
    int lane = threadIdx.x & 63;
    if (wid >= nE) return;
    int src = ei[wid];
    int dst = ei[nE + wid];
    float e = ew[wid] * We[lane];
    float q = QKVS[dst * 256 + lane];
    float k = QKVS[src * 256 + 64 + lane] + e;
    float p = q * k;
    for (int off = 32; off; off >>= 1) p += __shfl_down(p, off);
    if (lane == 0) {
        float logit = p * 0.125f;
        L[wid] = logit;
        atomicMax(&Menc[dst], enc_f(logit));
    }
}

// One wave per edge: a = exp(logit - m[dst]); S[dst]+=a; AG[dst][:] += a*(v[src]+ew*We)
__global__ __launch_bounds__(256) void edge_accum(
    const int* __restrict__ ei, const float* __restrict__ ew,
    const float* __restrict__ We, const float* __restrict__ QKVS,
    const float* __restrict__ L, const unsigned* __restrict__ Menc,
    float* __restrict__ S, float* __restrict__ AG, int nE)
{
    int wid = (int)((blockIdx.x * 256u + threadIdx.x) >> 6);
    int lane = threadIdx.x & 63;
    if (wid >= nE) return;
    int src = ei[wid];
    int dst = ei[nE + wid];
    float m = dec_f(Menc[dst]);
    float a = expf(L[wid] - m);
    float ve = QKVS[src * 256 + 128 + lane] + ew[wid] * We[lane];
    atomicAdd(&AG[dst * 64 + lane], a * ve);
    if (lane == 0) atomicAdd(&S[dst], a);
}

// H[i][c] = relu(AG[i][c]/(S[i]+1e-16) + sproj[i][c])
__global__ __launch_bounds__(256) void node_update(
    const float* __restrict__ AG, const float* __restrict__ S,
    const float* __restrict__ QKVS, float* __restrict__ H, int n)
{
    int idx = blockIdx.x * 256 + threadIdx.x;
    if (idx >= n * 64) return;
    int i = idx >> 6, c = idx & 63;
    float v = AG[idx] / (S[i] + 1e-16f) + QKVS[i * 256 + 192 + c];
    H[idx] = v > 0.f ? v : 0.f;
}

__global__ __launch_bounds__(256) void pool_kernel(
    const float* __restrict__ H, const int* __restrict__ batch,
    float* __restrict__ P, float* __restrict__ CNT, int n)
{
    int idx = blockIdx.x * 256 + threadIdx.x;
    if (idx >= n * 64) return;
    int i = idx >> 6, c = idx & 63;
    int g = batch[i];
    atomicAdd(&P[g * 64 + c], H[idx]);
    if (c == 0) atomicAdd(&CNT[g], 1.0f);
}

__global__ __launch_bounds__(256) void final_kernel(
    const float* __restrict__ P, const float* __restrict__ CNT,
    const float* __restrict__ Wl, const float* __restrict__ bl,
    float* __restrict__ out)
{
    int t = blockIdx.x * 256 + threadIdx.x;
    if (t >= NG * 2) return;
    int g = t >> 1, c = t & 1;
    float cnt = CNT[g];
    cnt = cnt > 1.f ? cnt : 1.f;
    float inv = 1.f / cnt;
    float acc = bl[c];
    for (int h = 0; h < 64; h++) acc += (P[g * 64 + h] * inv) * Wl[h * 2 + c];
    out[t] = acc;
}

extern "C" void kernel_launch(void* const* d_in, const int* in_sizes, int n_in,
                              void* d_out, int out_size, void* d_ws, size_t ws_size,
                              hipStream_t stream) {
    const float* x     = (const float*)d_in[0];
    const int*   ei    = (const int*)d_in[1];
    const float* ew    = (const float*)d_in[2];
    const int*   batch = (const int*)d_in[3];
    const float* Wq1 = (const float*)d_in[4];  const float* bq1 = (const float*)d_in[5];
    const float* Wk1 = (const float*)d_in[6];  const float* bk1 = (const float*)d_in[7];
    const float* Wv1 = (const float*)d_in[8];  const float* bv1 = (const float*)d_in[9];
    const float* We1 = (const float*)d_in[10];
    const float* Ws1 = (const float*)d_in[11]; const float* bs1 = (const float*)d_in[12];
    const float* Wq2 = (const float*)d_in[13]; const float* bq2 = (const float*)d_in[14];
    const float* Wk2 = (const float*)d_in[15]; const float* bk2 = (const float*)d_in[16];
    const float* Wv2 = (const float*)d_in[17]; const float* bv2 = (const float*)d_in[18];
    const float* We2 = (const float*)d_in[19];
    const float* Ws2 = (const float*)d_in[20]; const float* bs2 = (const float*)d_in[21];
    const float* Wl  = (const float*)d_in[22]; const float* bl  = (const float*)d_in[23];
    float* out = (float*)d_out;

    char* w = (char*)d_ws;
    float*    QKVS = (float*)w;    w += (size_t)NN * 256 * 4;
    float*    H    = (float*)w;    w += (size_t)NN * 64 * 4;
    float*    AG   = (float*)w;    w += (size_t)NN * 64 * 4;
    float*    L    = (float*)w;    w += (size_t)NE * 4;
    unsigned* M    = (unsigned*)w; w += (size_t)NN * 4;
    float*    S    = (float*)w;    w += (size_t)NN * 4;
    float*    P    = (float*)w;    w += (size_t)NG * 64 * 4;
    float*    CNT  = (float*)w;    w += (size_t)NG * 4;

    dim3 blk(256);
    int gProj = (NN + 15) / 16;
    int gEdge = (NE + 3) / 4;
    int gNode = (NN * 64 + 255) / 256;

    // ---- layer 1 ----
    hipMemsetAsync(AG, 0, (size_t)NN * 64 * 4, stream);
    hipMemsetAsync(M, 0, (size_t)NN * 4, stream);
    hipMemsetAsync(S, 0, (size_t)NN * 4, stream);
    hipMemsetAsync(P, 0, (size_t)(NG * 64 + NG) * 4, stream);

    proj4<<<gProj, blk, 0, stream>>>(x, Wq1, bq1, Wk1, bk1, Wv1, bv1, Ws1, bs1, QKVS, NN);
    edge_logits<<<gEdge, blk, 0, stream>>>(ei, ew, We1, QKVS, L, M, NE);
    edge_accum<<<gEdge, blk, 0, stream>>>(ei, ew, We1, QKVS, L, M, S, AG, NE);
    node_update<<<gNode, blk, 0, stream>>>(AG, S, QKVS, H, NN);

    // ---- layer 2 ----
    hipMemsetAsync(AG, 0, (size_t)NN * 64 * 4, stream);
    hipMemsetAsync(M, 0, (size_t)NN * 4, stream);
    hipMemsetAsync(S, 0, (size_t)NN * 4, stream);

    proj4<<<gProj, blk, 0, stream>>>(H, Wq2, bq2, Wk2, bk2, Wv2, bv2, Ws2, bs2, QKVS, NN);
    edge_logits<<<gEdge, blk, 0, stream>>>(ei, ew, We2, QKVS, L, M, NE);
    edge_accum<<<gEdge, blk, 0, stream>>>(ei, ew, We2, QKVS, L, M, S, AG, NE);
    node_update<<<gNode, blk, 0, stream>>>(AG, S, QKVS, H, NN);

    // ---- pooling + classifier ----
    pool_kernel<<<gNode, blk, 0, stream>>>(H, batch, P, CNT, NN);
    final_kernel<<<2, blk, 0, stream>>>(P, CNT, Wl, bl, out);
}

// Round 2
// 668.974 us; speedup vs baseline: 1.6011x; 1.6011x over previous
//
#include <hip/hip_runtime.h>
#include <math.h>

#define NN 50000
#define NE 800000
#define NG 256
#define NB ((NN + 255) / 256)   // 196 scan blocks

// Fused x@{W0,W1,W2,W3}+b -> out[N][256] (cols 0-63:q, 64-127:k, 128-191:v, 192-255:s)
__global__ __launch_bounds__(256) void proj4(
    const float* __restrict__ X,
    const float* __restrict__ W0, const float* __restrict__ b0,
    const float* __restrict__ W1, const float* __restrict__ b1,
    const float* __restrict__ W2, const float* __restrict__ b2,
    const float* __restrict__ W3, const float* __restrict__ b3,
    float* __restrict__ out, int n)
{
    __shared__ float Xs[16][64];
    int r0 = blockIdx.x * 16;
    int tid = threadIdx.x;
    for (int i = tid; i < 16 * 64; i += 256) {
        int r = i >> 6, c = i & 63;
        int gr = r0 + r;
        Xs[r][c] = (gr < n) ? X[gr * 64 + c] : 0.f;
    }
    __syncthreads();
    int c = tid & 63;
    int m = tid >> 6;
    const float* W = (m == 0) ? W0 : (m == 1) ? W1 : (m == 2) ? W2 : W3;
    const float* B = (m == 0) ? b0 : (m == 1) ? b1 : (m == 2) ? b2 : b3;
    float bias = B[c];
    float acc[16];
#pragma unroll
    for (int r = 0; r < 16; r++) acc[r] = bias;
    for (int k = 0; k < 64; k++) {
        float w = W[k * 64 + c];
#pragma unroll
        for (int r = 0; r < 16; r++) acc[r] += Xs[r][k] * w;
    }
    for (int r = 0; r < 16; r++) {
        int gr = r0 + r;
        if (gr < n) out[gr * 256 + tid] = acc[r];
    }
}

// ---------- CSR build (once per call, reused by both layers) ----------
__global__ __launch_bounds__(256) void deg_count(const int* __restrict__ ei,
                                                 int* __restrict__ deg) {
    int e = blockIdx.x * 256 + threadIdx.x;
    if (e >= NE) return;
    atomicAdd(&deg[ei[NE + e]], 1);
}

__global__ __launch_bounds__(256) void scan_block(const int* __restrict__ deg,
                                                  int* __restrict__ off,
                                                  int* __restrict__ bsum) {
    __shared__ int buf[256];
    int i = blockIdx.x * 256 + threadIdx.x;
    int v = (i < NN) ? deg[i] : 0;
    buf[threadIdx.x] = v;
    __syncthreads();
    for (int o = 1; o < 256; o <<= 1) {
        int t = (threadIdx.x >= o) ? buf[threadIdx.x - o] : 0;
        __syncthreads();
        buf[threadIdx.x] += t;
        __syncthreads();
    }
    if (i < NN) off[i + 1] = buf[threadIdx.x];
    if (threadIdx.x == 255) bsum[blockIdx.x] = buf[255];
}

__global__ __launch_bounds__(256) void scan_tot(const int* __restrict__ bsum,
                                                int* __restrict__ boff) {
    __shared__ int buf[256];
    int v = (threadIdx.x < NB) ? bsum[threadIdx.x] : 0;
    buf[threadIdx.x] = v;
    __syncthreads();
    for (int o = 1; o < 256; o <<= 1) {
        int t = (threadIdx.x >= o) ? buf[threadIdx.x - o] : 0;
        __syncthreads();
        buf[threadIdx.x] += t;
        __syncthreads();
    }
    boff[threadIdx.x] = (threadIdx.x == 0) ? 0 : buf[threadIdx.x - 1];
}

__global__ __launch_bounds__(256) void scan_add(int* __restrict__ off,
                                                const int* __restrict__ boff) {
    int i = blockIdx.x * 256 + threadIdx.x;
    if (i < NN) off[i + 1] += boff[blockIdx.x];
    if (i == 0) off[0] = 0;
}

__global__ __launch_bounds__(256) void csr_fill(const int* __restrict__ ei,
                                                const float* __restrict__ ew,
                                                int* __restrict__ cur,
                                                int* __restrict__ esrc,
                                                float* __restrict__ ews) {
    int e = blockIdx.x * 256 + threadIdx.x;
    if (e >= NE) return;
    int dst = ei[NE + e];
    int pos = atomicAdd(&cur[dst], 1);
    esrc[pos] = ei[e];
    ews[pos] = ew[e];
}

// ---------- fused attention: one wave per dst node, online softmax ----------
__global__ __launch_bounds__(256) void attn_fused(
    const int* __restrict__ off, const int* __restrict__ esrc,
    const float* __restrict__ ews, const float* __restrict__ We,
    const float* __restrict__ QKVS, float* __restrict__ H, int n)
{
    int wid = blockIdx.x * 4 + (threadIdx.x >> 6);
    int lane = threadIdx.x & 63;
    if (wid >= n) return;
    float we = We[lane];
    float q = QKVS[wid * 256 + lane];
    int e0 = off[wid], e1 = off[wid + 1];
    float m = -INFINITY, s = 0.f, acc = 0.f;
    for (int e = e0; e < e1; e++) {
        int src = esrc[e];
        float w = ews[e];
        float ke = QKVS[src * 256 + 64 + lane] + w * we;
        float p = q * ke;
#pragma unroll
        for (int o = 1; o < 64; o <<= 1) p += __shfl_xor(p, o);
        float logit = p * 0.125f;
        float ve = QKVS[src * 256 + 128 + lane] + w * we;
        float mn = fmaxf(m, logit);
        float sc = expf(m - mn);
        float a = expf(logit - mn);
        s = s * sc + a;
        acc = acc * sc + a * ve;
        m = mn;
    }
    float outv = acc / (s + 1e-16f) + QKVS[wid * 256 + 192 + lane];
    H[wid * 64 + lane] = fmaxf(outv, 0.f);
}

__global__ __launch_bounds__(256) void pool_kernel(
    const float* __restrict__ H, const int* __restrict__ batch,
    float* __restrict__ P, float* __restrict__ CNT, int n)
{
    int idx = blockIdx.x * 256 + threadIdx.x;
    if (idx >= n * 64) return;
    int i = idx >> 6, c = idx & 63;
    int g = batch[i];
    atomicAdd(&P[g * 64 + c], H[idx]);
    if (c == 0) atomicAdd(&CNT[g], 1.0f);
}

__global__ __launch_bounds__(256) void final_kernel(
    const float* __restrict__ P, const float* __restrict__ CNT,
    const float* __restrict__ Wl, const float* __restrict__ bl,
    float* __restrict__ out)
{
    int t = blockIdx.x * 256 + threadIdx.x;
    if (t >= NG * 2) return;
    int g = t >> 1, c = t & 1;
    float cnt = CNT[g];
    cnt = cnt > 1.f ? cnt : 1.f;
    float inv = 1.f / cnt;
    float acc = bl[c];
    for (int h = 0; h < 64; h++) acc += (P[g * 64 + h] * inv) * Wl[h * 2 + c];
    out[t] = acc;
}

extern "C" void kernel_launch(void* const* d_in, const int* in_sizes, int n_in,
                              void* d_out, int out_size, void* d_ws, size_t ws_size,
                              hipStream_t stream) {
    const float* x     = (const float*)d_in[0];
    const int*   ei    = (const int*)d_in[1];
    const float* ew    = (const float*)d_in[2];
    const int*   batch = (const int*)d_in[3];
    const float* Wq1 = (const float*)d_in[4];  const float* bq1 = (const float*)d_in[5];
    const float* Wk1 = (const float*)d_in[6];  const float* bk1 = (const float*)d_in[7];
    const float* Wv1 = (const float*)d_in[8];  const float* bv1 = (const float*)d_in[9];
    const float* We1 = (const float*)d_in[10];
    const float* Ws1 = (const float*)d_in[11]; const float* bs1 = (const float*)d_in[12];
    const float* Wq2 = (const float*)d_in[13]; const float* bq2 = (const float*)d_in[14];
    const float* Wk2 = (const float*)d_in[15]; const float* bk2 = (const float*)d_in[16];
    const float* Wv2 = (const float*)d_in[17]; const float* bv2 = (const float*)d_in[18];
    const float* We2 = (const float*)d_in[19];
    const float* Ws2 = (const float*)d_in[20]; const float* bs2 = (const float*)d_in[21];
    const float* Wl  = (const float*)d_in[22]; const float* bl  = (const float*)d_in[23];
    float* out = (float*)d_out;

    char* w = (char*)d_ws;
    float* QKVS = (float*)w; w += (size_t)NN * 256 * 4;
    float* H    = (float*)w; w += (size_t)NN * 64 * 4;
    int*   off  = (int*)w;   w += (size_t)(NN + 1) * 4;
    int*   deg  = (int*)w;   w += (size_t)NN * 4;
    int*   cur  = (int*)w;   w += (size_t)NN * 4;
    int*   bsum = (int*)w;   w += 256 * 4;
    int*   boff = (int*)w;   w += 256 * 4;
    int*   esrc = (int*)w;   w += (size_t)NE * 4;
    float* ews  = (float*)w; w += (size_t)NE * 4;
    float* P    = (float*)w; w += (size_t)NG * 64 * 4;
    float* CNT  = (float*)w; w += (size_t)NG * 4;

    dim3 blk(256);
    int gProj = (NN + 15) / 16;
    int gEdge = (NE + 255) / 256;
    int gNode = (NN * 64 + 255) / 256;
    int gAttn = (NN + 3) / 4;

    // ---- CSR build (dst-sorted adjacency), shared by both layers ----
    hipMemsetAsync(deg, 0, (size_t)NN * 4, stream);
    hipMemsetAsync(P, 0, (size_t)(NG * 64 + NG) * 4, stream);
    deg_count<<<gEdge, blk, 0, stream>>>(ei, deg);
    scan_block<<<NB, blk, 0, stream>>>(deg, off, bsum);
    scan_tot<<<1, blk, 0, stream>>>(bsum, boff);
    scan_add<<<NB, blk, 0, stream>>>(off, boff);
    hipMemcpyAsync(cur, off, (size_t)NN * 4, hipMemcpyDeviceToDevice, stream);
    csr_fill<<<gEdge, blk, 0, stream>>>(ei, ew, cur, esrc, ews);

    // ---- layer 1 ----
    proj4<<<gProj, blk, 0, stream>>>(x, Wq1, bq1, Wk1, bk1, Wv1, bv1, Ws1, bs1, QKVS, NN);
    attn_fused<<<gAttn, blk, 0, stream>>>(off, esrc, ews, We1, QKVS, H, NN);

    // ---- layer 2 ----
    proj4<<<gProj, blk, 0, stream>>>(H, Wq2, bq2, Wk2, bk2, Wv2, bv2, Ws2, bs2, QKVS, NN);
    attn_fused<<<gAttn, blk, 0, stream>>>(off, esrc, ews, We2, QKVS, H, NN);

    // ---- pooling + classifier ----
    pool_kernel<<<gNode, blk, 0, stream>>>(H, batch, P, CNT, NN);
    final_kernel<<<2, blk, 0, stream>>>(P, CNT, Wl, bl, out);
}

// Round 3
// 545.589 us; speedup vs baseline: 1.9632x; 1.2262x over previous
//
#include <hip/hip_runtime.h>
#include <math.h>

#define NN 50000
#define NE 800000
#define NG 256
#define NB ((NN + 255) / 256)   // 196 scan blocks

// Fused x@{W0,W1,W2,W3}+b -> out[N][256] (cols 0-63:q, 64-127:k, 128-191:v, 192-255:s)
__global__ __launch_bounds__(256) void proj4(
    const float* __restrict__ X,
    const float* __restrict__ W0, const float* __restrict__ b0,
    const float* __restrict__ W1, const float* __restrict__ b1,
    const float* __restrict__ W2, const float* __restrict__ b2,
    const float* __restrict__ W3, const float* __restrict__ b3,
    float* __restrict__ out, int n)
{
    __shared__ float Xs[16][64];
    int r0 = blockIdx.x * 16;
    int tid = threadIdx.x;
    for (int i = tid; i < 16 * 64; i += 256) {
        int r = i >> 6, c = i & 63;
        int gr = r0 + r;
        Xs[r][c] = (gr < n) ? X[gr * 64 + c] : 0.f;
    }
    __syncthreads();
    int c = tid & 63;
    int m = tid >> 6;
    const float* W = (m == 0) ? W0 : (m == 1) ? W1 : (m == 2) ? W2 : W3;
    const float* B = (m == 0) ? b0 : (m == 1) ? b1 : (m == 2) ? b2 : b3;
    float bias = B[c];
    float acc[16];
#pragma unroll
    for (int r = 0; r < 16; r++) acc[r] = bias;
    for (int k = 0; k < 64; k++) {
        float w = W[k * 64 + c];
#pragma unroll
        for (int r = 0; r < 16; r++) acc[r] += Xs[r][k] * w;
    }
    for (int r = 0; r < 16; r++) {
        int gr = r0 + r;
        if (gr < n) out[gr * 256 + tid] = acc[r];
    }
}

// ---------- CSR build (once per call, reused by both layers) ----------
__global__ __launch_bounds__(256) void deg_count(const int* __restrict__ ei,
                                                 int* __restrict__ deg) {
    int e = blockIdx.x * 256 + threadIdx.x;
    if (e >= NE) return;
    atomicAdd(&deg[ei[NE + e]], 1);
}

__global__ __launch_bounds__(256) void scan_block(const int* __restrict__ deg,
                                                  int* __restrict__ off,
                                                  int* __restrict__ bsum) {
    __shared__ int buf[256];
    int i = blockIdx.x * 256 + threadIdx.x;
    int v = (i < NN) ? deg[i] : 0;
    buf[threadIdx.x] = v;
    __syncthreads();
    for (int o = 1; o < 256; o <<= 1) {
        int t = (threadIdx.x >= o) ? buf[threadIdx.x - o] : 0;
        __syncthreads();
        buf[threadIdx.x] += t;
        __syncthreads();
    }
    if (i < NN) off[i + 1] = buf[threadIdx.x];
    if (threadIdx.x == 255) bsum[blockIdx.x] = buf[255];
}

__global__ __launch_bounds__(256) void scan_tot(const int* __restrict__ bsum,
                                                int* __restrict__ boff) {
    __shared__ int buf[256];
    int v = (threadIdx.x < NB) ? bsum[threadIdx.x] : 0;
    buf[threadIdx.x] = v;
    __syncthreads();
    for (int o = 1; o < 256; o <<= 1) {
        int t = (threadIdx.x >= o) ? buf[threadIdx.x - o] : 0;
        __syncthreads();
        buf[threadIdx.x] += t;
        __syncthreads();
    }
    boff[threadIdx.x] = (threadIdx.x == 0) ? 0 : buf[threadIdx.x - 1];
}

__global__ __launch_bounds__(256) void scan_add(int* __restrict__ off,
                                                const int* __restrict__ boff) {
    int i = blockIdx.x * 256 + threadIdx.x;
    if (i < NN) off[i + 1] += boff[blockIdx.x];
    if (i == 0) off[0] = 0;
}

__global__ __launch_bounds__(256) void csr_fill(const int* __restrict__ ei,
                                                const float* __restrict__ ew,
                                                int* __restrict__ cur,
                                                int* __restrict__ esrc,
                                                float* __restrict__ ews) {
    int e = blockIdx.x * 256 + threadIdx.x;
    if (e >= NE) return;
    int dst = ei[NE + e];
    int pos = atomicAdd(&cur[dst], 1);
    esrc[pos] = ei[e];
    ews[pos] = ew[e];
}

// ---------- fused attention: one wave per dst node, online softmax ----------
__global__ __launch_bounds__(256) void attn_fused(
    const int* __restrict__ off, const int* __restrict__ esrc,
    const float* __restrict__ ews, const float* __restrict__ We,
    const float* __restrict__ QKVS, float* __restrict__ H, int n)
{
    int wid = blockIdx.x * 4 + (threadIdx.x >> 6);
    int lane = threadIdx.x & 63;
    if (wid >= n) return;
    float we = We[lane];
    float q = QKVS[wid * 256 + lane];
    int e0 = off[wid], e1 = off[wid + 1];
    float m = -INFINITY, s = 0.f, acc = 0.f;
    for (int e = e0; e < e1; e++) {
        int src = esrc[e];
        float w = ews[e];
        float ke = QKVS[src * 256 + 64 + lane] + w * we;
        float ve = QKVS[src * 256 + 128 + lane] + w * we;
        float p = q * ke;
#pragma unroll
        for (int o = 1; o < 64; o <<= 1) p += __shfl_xor(p, o);
        float logit = p * 0.125f;
        float mn = fmaxf(m, logit);
        float sc = expf(m - mn);
        float a = expf(logit - mn);
        s = s * sc + a;
        acc = acc * sc + a * ve;
        m = mn;
    }
    float outv = acc / (s + 1e-16f) + QKVS[wid * 256 + 192 + lane];
    H[wid * 64 + lane] = fmaxf(outv, 0.f);
}

// ---------- segmented mean-pool: one wave per 64-node chunk ----------
// batch is sorted, so each chunk spans ~1-2 groups; flush per boundary.
__global__ __launch_bounds__(256) void pool_kernel(
    const float* __restrict__ H, const int* __restrict__ batch,
    float* __restrict__ P, float* __restrict__ CNT, int n)
{
    int wave = blockIdx.x * 4 + (threadIdx.x >> 6);
    int lane = threadIdx.x & 63;
    int base = wave * 64;
    if (base >= n) return;
    int end = base + 64; if (end > n) end = n;
    int g = batch[base];
    float acc = 0.f, cnt = 0.f;
    for (int i = base; i < end; i++) {
        int gi = batch[i];
        if (gi != g) {
            atomicAdd(&P[g * 64 + lane], acc);
            if (lane == 0) atomicAdd(&CNT[g], cnt);
            acc = 0.f; cnt = 0.f; g = gi;
        }
        acc += H[i * 64 + lane];
        cnt += 1.f;
    }
    atomicAdd(&P[g * 64 + lane], acc);
    if (lane == 0) atomicAdd(&CNT[g], cnt);
}

__global__ __launch_bounds__(256) void final_kernel(
    const float* __restrict__ P, const float* __restrict__ CNT,
    const float* __restrict__ Wl, const float* __restrict__ bl,
    float* __restrict__ out)
{
    int t = blockIdx.x * 256 + threadIdx.x;
    if (t >= NG * 2) return;
    int g = t >> 1, c = t & 1;
    float cnt = CNT[g];
    cnt = cnt > 1.f ? cnt : 1.f;
    float inv = 1.f / cnt;
    float acc = bl[c];
    for (int h = 0; h < 64; h++) acc += (P[g * 64 + h] * inv) * Wl[h * 2 + c];
    out[t] = acc;
}

extern "C" void kernel_launch(void* const* d_in, const int* in_sizes, int n_in,
                              void* d_out, int out_size, void* d_ws, size_t ws_size,
                              hipStream_t stream) {
    const float* x     = (const float*)d_in[0];
    const int*   ei    = (const int*)d_in[1];
    const float* ew    = (const float*)d_in[2];
    const int*   batch = (const int*)d_in[3];
    const float* Wq1 = (const float*)d_in[4];  const float* bq1 = (const float*)d_in[5];
    const float* Wk1 = (const float*)d_in[6];  const float* bk1 = (const float*)d_in[7];
    const float* Wv1 = (const float*)d_in[8];  const float* bv1 = (const float*)d_in[9];
    const float* We1 = (const float*)d_in[10];
    const float* Ws1 = (const float*)d_in[11]; const float* bs1 = (const float*)d_in[12];
    const float* Wq2 = (const float*)d_in[13]; const float* bq2 = (const float*)d_in[14];
    const float* Wk2 = (const float*)d_in[15]; const float* bk2 = (const float*)d_in[16];
    const float* Wv2 = (const float*)d_in[17]; const float* bv2 = (const float*)d_in[18];
    const float* We2 = (const float*)d_in[19];
    const float* Ws2 = (const float*)d_in[20]; const float* bs2 = (const float*)d_in[21];
    const float* Wl  = (const float*)d_in[22]; const float* bl  = (const float*)d_in[23];
    float* out = (float*)d_out;

    char* w = (char*)d_ws;
    float* QKVS = (float*)w; w += (size_t)NN * 256 * 4;
    float* H    = (float*)w; w += (size_t)NN * 64 * 4;
    int*   off  = (int*)w;   w += (size_t)(NN + 1) * 4;
    int*   deg  = (int*)w;   w += (size_t)NN * 4;
    int*   cur  = (int*)w;   w += (size_t)NN * 4;
    int*   bsum = (int*)w;   w += 256 * 4;
    int*   boff = (int*)w;   w += 256 * 4;
    int*   esrc = (int*)w;   w += (size_t)NE * 4;
    float* ews  = (float*)w; w += (size_t)NE * 4;
    float* P    = (float*)w; w += (size_t)NG * 64 * 4;
    float* CNT  = (float*)w; w += (size_t)NG * 4;

    dim3 blk(256);
    int gProj = (NN + 15) / 16;
    int gEdge = (NE + 255) / 256;
    int gAttn = (NN + 3) / 4;
    int gPool = (NN + 255) / 256;   // 4 waves/block, 64 nodes/wave

    // ---- CSR build (dst-sorted adjacency), shared by both layers ----
    hipMemsetAsync(deg, 0, (size_t)NN * 4, stream);
    hipMemsetAsync(P, 0, (size_t)(NG * 64 + NG) * 4, stream);
    deg_count<<<gEdge, blk, 0, stream>>>(ei, deg);
    scan_block<<<NB, blk, 0, stream>>>(deg, off, bsum);
    scan_tot<<<1, blk, 0, stream>>>(bsum, boff);
    scan_add<<<NB, blk, 0, stream>>>(off, boff);
    hipMemcpyAsync(cur, off, (size_t)NN * 4, hipMemcpyDeviceToDevice, stream);
    csr_fill<<<gEdge, blk, 0, stream>>>(ei, ew, cur, esrc, ews);

    // ---- layer 1 ----
    proj4<<<gProj, blk, 0, stream>>>(x, Wq1, bq1, Wk1, bk1, Wv1, bv1, Ws1, bs1, QKVS, NN);
    attn_fused<<<gAttn, blk, 0, stream>>>(off, esrc, ews, We1, QKVS, H, NN);

    // ---- layer 2 ----
    proj4<<<gProj, blk, 0, stream>>>(H, Wq2, bq2, Wk2, bk2, Wv2, bv2, Ws2, bs2, QKVS, NN);
    attn_fused<<<gAttn, blk, 0, stream>>>(off, esrc, ews, We2, QKVS, H, NN);

    // ---- pooling + classifier ----
    pool_kernel<<<gPool, blk, 0, stream>>>(H, batch, P, CNT, NN);
    final_kernel<<<2, blk, 0, stream>>>(P, CNT, Wl, bl, out);
}

// Round 4
// 440.807 us; speedup vs baseline: 2.4299x; 1.2377x over previous
//
#include <hip/hip_runtime.h>
#include <math.h>

#define NN 50000
#define NE 800000
#define NG 256
#define NB ((NN + 255) / 256)   // 196 scan blocks

// Fused x@{W0,W1,W2,W3}+b -> out[N][256] (cols 0-63:q, 64-127:k, 128-191:v, 192-255:s)
__global__ __launch_bounds__(256) void proj4(
    const float* __restrict__ X,
    const float* __restrict__ W0, const float* __restrict__ b0,
    const float* __restrict__ W1, const float* __restrict__ b1,
    const float* __restrict__ W2, const float* __restrict__ b2,
    const float* __restrict__ W3, const float* __restrict__ b3,
    float* __restrict__ out, int n)
{
    __shared__ float Xs[16][64];
    int r0 = blockIdx.x * 16;
    int tid = threadIdx.x;
    for (int i = tid; i < 16 * 64; i += 256) {
        int r = i >> 6, c = i & 63;
        int gr = r0 + r;
        Xs[r][c] = (gr < n) ? X[gr * 64 + c] : 0.f;
    }
    __syncthreads();
    int c = tid & 63;
    int m = tid >> 6;
    const float* W = (m == 0) ? W0 : (m == 1) ? W1 : (m == 2) ? W2 : W3;
    const float* B = (m == 0) ? b0 : (m == 1) ? b1 : (m == 2) ? b2 : b3;
    float bias = B[c];
    float acc[16];
#pragma unroll
    for (int r = 0; r < 16; r++) acc[r] = bias;
    for (int k = 0; k < 64; k++) {
        float w = W[k * 64 + c];
#pragma unroll
        for (int r = 0; r < 16; r++) acc[r] += Xs[r][k] * w;
    }
    for (int r = 0; r < 16; r++) {
        int gr = r0 + r;
        if (gr < n) out[gr * 256 + tid] = acc[r];
    }
}

// ---------- CSR build (once per call, reused by both layers) ----------
__global__ __launch_bounds__(256) void deg_count(const int* __restrict__ ei,
                                                 int* __restrict__ deg) {
    int e = blockIdx.x * 256 + threadIdx.x;
    if (e >= NE) return;
    atomicAdd(&deg[ei[NE + e]], 1);
}

__global__ __launch_bounds__(256) void scan_block(const int* __restrict__ deg,
                                                  int* __restrict__ off,
                                                  int* __restrict__ bsum) {
    __shared__ int buf[256];
    int i = blockIdx.x * 256 + threadIdx.x;
    int v = (i < NN) ? deg[i] : 0;
    buf[threadIdx.x] = v;
    __syncthreads();
    for (int o = 1; o < 256; o <<= 1) {
        int t = (threadIdx.x >= o) ? buf[threadIdx.x - o] : 0;
        __syncthreads();
        buf[threadIdx.x] += t;
        __syncthreads();
    }
    if (i < NN) off[i + 1] = buf[threadIdx.x];
    if (threadIdx.x == 255) bsum[blockIdx.x] = buf[255];
}

__global__ __launch_bounds__(256) void scan_tot(const int* __restrict__ bsum,
                                                int* __restrict__ boff) {
    __shared__ int buf[256];
    int v = (threadIdx.x < NB) ? bsum[threadIdx.x] : 0;
    buf[threadIdx.x] = v;
    __syncthreads();
    for (int o = 1; o < 256; o <<= 1) {
        int t = (threadIdx.x >= o) ? buf[threadIdx.x - o] : 0;
        __syncthreads();
        buf[threadIdx.x] += t;
        __syncthreads();
    }
    boff[threadIdx.x] = (threadIdx.x == 0) ? 0 : buf[threadIdx.x - 1];
}

__global__ __launch_bounds__(256) void scan_add(int* __restrict__ off,
                                                const int* __restrict__ boff) {
    int i = blockIdx.x * 256 + threadIdx.x;
    if (i < NN) off[i + 1] += boff[blockIdx.x];
    if (i == 0) off[0] = 0;
}

__global__ __launch_bounds__(256) void csr_fill(const int* __restrict__ ei,
                                                const float* __restrict__ ew,
                                                int* __restrict__ cur,
                                                int* __restrict__ esrc,
                                                float* __restrict__ ews) {
    int e = blockIdx.x * 256 + threadIdx.x;
    if (e >= NE) return;
    int dst = ei[NE + e];
    int pos = atomicAdd(&cur[dst], 1);
    esrc[pos] = ei[e];
    ews[pos] = ew[e];
}

// ---------- fused attention: one wave per dst node, 4 edges/iter ----------
// 16 lanes per edge, float4 per lane. Online softmax per group, merged at end.
// logit = (q.k[src] + w*(q.We))/8 ; agg = (Σ a*v[src] + (Σ a*w)*We) / Σ a
__global__ __launch_bounds__(256) void attn_fused(
    const int* __restrict__ off, const int* __restrict__ esrc,
    const float* __restrict__ ews, const float* __restrict__ We,
    const float* __restrict__ QKVS, float* __restrict__ H, int n)
{
    int wid = blockIdx.x * 4 + (threadIdx.x >> 6);
    if (wid >= n) return;
    int lane = threadIdx.x & 63;
    int g = lane >> 4;       // edge group 0..3
    int c = lane & 15;       // feature-quad index 0..15

    const float4* Q4 = (const float4*)(QKVS + (size_t)wid * 256);
    float4 q4 = Q4[c];
    float4 we4 = ((const float4*)We)[c];

    // qwe = dot(q, We), reduced within the 16-lane group
    float p = q4.x * we4.x + q4.y * we4.y + q4.z * we4.z + q4.w * we4.w;
    p += __shfl_xor(p, 1); p += __shfl_xor(p, 2);
    p += __shfl_xor(p, 4); p += __shfl_xor(p, 8);
    float qwe = p;

    int e0 = off[wid], e1 = off[wid + 1];
    float m = -INFINITY, s = 0.f, aw = 0.f;
    float4 acc = make_float4(0.f, 0.f, 0.f, 0.f);

    for (int e = e0 + g; e < e1; e += 4) {
        int src = esrc[e];
        float w = ews[e];
        const float4* R4 = (const float4*)(QKVS + (size_t)src * 256 + 64);
        float4 k4 = R4[c];        // k row
        float4 v4 = R4[16 + c];   // v row (next 64 floats)
        float d = q4.x * k4.x + q4.y * k4.y + q4.z * k4.z + q4.w * k4.w;
        d += __shfl_xor(d, 1); d += __shfl_xor(d, 2);
        d += __shfl_xor(d, 4); d += __shfl_xor(d, 8);
        float logit = (d + w * qwe) * 0.125f;
        float mn = fmaxf(m, logit);
        float sc = expf(m - mn);       // m=-inf first iter -> 0, no NaN
        float a = expf(logit - mn);
        s = s * sc + a;
        aw = aw * sc + a * w;
        acc.x = acc.x * sc + a * v4.x;
        acc.y = acc.y * sc + a * v4.y;
        acc.z = acc.z * sc + a * v4.z;
        acc.w = acc.w * sc + a * v4.w;
        m = mn;
    }

    // merge the 4 groups' online-softmax states (xor 16, then 32)
#pragma unroll
    for (int o = 16; o <= 32; o <<= 1) {
        float m2 = __shfl_xor(m, o);
        float s2 = __shfl_xor(s, o);
        float aw2 = __shfl_xor(aw, o);
        float ax = __shfl_xor(acc.x, o), ay = __shfl_xor(acc.y, o);
        float az = __shfl_xor(acc.z, o), a_w = __shfl_xor(acc.w, o);
        float mn = fmaxf(m, m2);
        float sc1 = (m == mn) ? 1.f : expf(m - mn);    // guards -inf/-inf
        float sc2 = (m2 == mn) ? 1.f : expf(m2 - mn);
        s = s * sc1 + s2 * sc2;
        aw = aw * sc1 + aw2 * sc2;
        acc.x = acc.x * sc1 + ax * sc2;
        acc.y = acc.y * sc1 + ay * sc2;
        acc.z = acc.z * sc1 + az * sc2;
        acc.w = acc.w * sc1 + a_w * sc2;
        m = mn;
    }

    if (g == 0) {
        float inv = 1.f / (s + 1e-16f);
        float4 sp4 = Q4[48 + c];   // sproj at cols 192..255
        float4 o4;
        o4.x = fmaxf((acc.x + aw * we4.x) * inv + sp4.x, 0.f);
        o4.y = fmaxf((acc.y + aw * we4.y) * inv + sp4.y, 0.f);
        o4.z = fmaxf((acc.z + aw * we4.z) * inv + sp4.z, 0.f);
        o4.w = fmaxf((acc.w + aw * we4.w) * inv + sp4.w, 0.f);
        ((float4*)(H + (size_t)wid * 64))[c] = o4;
    }
}

// ---------- segmented mean-pool: one wave per 64-node chunk ----------
__global__ __launch_bounds__(256) void pool_kernel(
    const float* __restrict__ H, const int* __restrict__ batch,
    float* __restrict__ P, float* __restrict__ CNT, int n)
{
    int wave = blockIdx.x * 4 + (threadIdx.x >> 6);
    int lane = threadIdx.x & 63;
    int base = wave * 64;
    if (base >= n) return;
    int end = base + 64; if (end > n) end = n;
    int g = batch[base];
    float acc = 0.f, cnt = 0.f;
    for (int i = base; i < end; i++) {
        int gi = batch[i];
        if (gi != g) {
            atomicAdd(&P[g * 64 + lane], acc);
            if (lane == 0) atomicAdd(&CNT[g], cnt);
            acc = 0.f; cnt = 0.f; g = gi;
        }
        acc += H[i * 64 + lane];
        cnt += 1.f;
    }
    atomicAdd(&P[g * 64 + lane], acc);
    if (lane == 0) atomicAdd(&CNT[g], cnt);
}

__global__ __launch_bounds__(256) void final_kernel(
    const float* __restrict__ P, const float* __restrict__ CNT,
    const float* __restrict__ Wl, const float* __restrict__ bl,
    float* __restrict__ out)
{
    int t = blockIdx.x * 256 + threadIdx.x;
    if (t >= NG * 2) return;
    int g = t >> 1, c = t & 1;
    float cnt = CNT[g];
    cnt = cnt > 1.f ? cnt : 1.f;
    float inv = 1.f / cnt;
    float acc = bl[c];
    for (int h = 0; h < 64; h++) acc += (P[g * 64 + h] * inv) * Wl[h * 2 + c];
    out[t] = acc;
}

extern "C" void kernel_launch(void* const* d_in, const int* in_sizes, int n_in,
                              void* d_out, int out_size, void* d_ws, size_t ws_size,
                              hipStream_t stream) {
    const float* x     = (const float*)d_in[0];
    const int*   ei    = (const int*)d_in[1];
    const float* ew    = (const float*)d_in[2];
    const int*   batch = (const int*)d_in[3];
    const float* Wq1 = (const float*)d_in[4];  const float* bq1 = (const float*)d_in[5];
    const float* Wk1 = (const float*)d_in[6];  const float* bk1 = (const float*)d_in[7];
    const float* Wv1 = (const float*)d_in[8];  const float* bv1 = (const float*)d_in[9];
    const float* We1 = (const float*)d_in[10];
    const float* Ws1 = (const float*)d_in[11]; const float* bs1 = (const float*)d_in[12];
    const float* Wq2 = (const float*)d_in[13]; const float* bq2 = (const float*)d_in[14];
    const float* Wk2 = (const float*)d_in[15]; const float* bk2 = (const float*)d_in[16];
    const float* Wv2 = (const float*)d_in[17]; const float* bv2 = (const float*)d_in[18];
    const float* We2 = (const float*)d_in[19];
    const float* Ws2 = (const float*)d_in[20]; const float* bs2 = (const float*)d_in[21];
    const float* Wl  = (const float*)d_in[22]; const float* bl  = (const float*)d_in[23];
    float* out = (float*)d_out;

    char* w = (char*)d_ws;
    float* QKVS = (float*)w; w += (size_t)NN * 256 * 4;
    float* H    = (float*)w; w += (size_t)NN * 64 * 4;
    int*   off  = (int*)w;   w += (size_t)(NN + 1) * 4;
    int*   deg  = (int*)w;   w += (size_t)NN * 4;
    int*   cur  = (int*)w;   w += (size_t)NN * 4;
    int*   bsum = (int*)w;   w += 256 * 4;
    int*   boff = (int*)w;   w += 256 * 4;
    int*   esrc = (int*)w;   w += (size_t)NE * 4;
    float* ews  = (float*)w; w += (size_t)NE * 4;
    float* P    = (float*)w; w += (size_t)NG * 64 * 4;
    float* CNT  = (float*)w; w += (size_t)NG * 4;

    dim3 blk(256);
    int gProj = (NN + 15) / 16;
    int gEdge = (NE + 255) / 256;
    int gAttn = (NN + 3) / 4;
    int gPool = (NN + 255) / 256;   // 4 waves/block, 64 nodes/wave

    // ---- CSR build (dst-sorted adjacency), shared by both layers ----
    hipMemsetAsync(deg, 0, (size_t)NN * 4, stream);
    hipMemsetAsync(P, 0, (size_t)(NG * 64 + NG) * 4, stream);
    deg_count<<<gEdge, blk, 0, stream>>>(ei, deg);
    scan_block<<<NB, blk, 0, stream>>>(deg, off, bsum);
    scan_tot<<<1, blk, 0, stream>>>(bsum, boff);
    scan_add<<<NB, blk, 0, stream>>>(off, boff);
    hipMemcpyAsync(cur, off, (size_t)NN * 4, hipMemcpyDeviceToDevice, stream);
    csr_fill<<<gEdge, blk, 0, stream>>>(ei, ew, cur, esrc, ews);

    // ---- layer 1 ----
    proj4<<<gProj, blk, 0, stream>>>(x, Wq1, bq1, Wk1, bk1, Wv1, bv1, Ws1, bs1, QKVS, NN);
    attn_fused<<<gAttn, blk, 0, stream>>>(off, esrc, ews, We1, QKVS, H, NN);

    // ---- layer 2 ----
    proj4<<<gProj, blk, 0, stream>>>(H, Wq2, bq2, Wk2, bk2, Wv2, bv2, Ws2, bs2, QKVS, NN);
    attn_fused<<<gAttn, blk, 0, stream>>>(off, esrc, ews, We2, QKVS, H, NN);

    // ---- pooling + classifier ----
    pool_kernel<<<gPool, blk, 0, stream>>>(H, batch, P, CNT, NN);
    final_kernel<<<2, blk, 0, stream>>>(P, CNT, Wl, bl, out);
}

// Round 6
// 436.994 us; speedup vs baseline: 2.4511x; 1.0087x over previous
//
#include <hip/hip_runtime.h>
#include <math.h>

#define NN 50000
#define NE 800000
#define NG 256
#define NB ((NN + 255) / 256)   // 196 scan blocks

// Kahan compensated add: sum += val (with compensation c)
#define KAH(sum, comp, val) { float _y = (val) - (comp); float _t = (sum) + _y; \
                              (comp) = (_t - (sum)) - _y; (sum) = _t; }

// Fused x@{W0,W1,W2,W3}+b -> out[N][256] (cols 0-63:q, 64-127:k, 128-191:v, 192-255:s)
__global__ __launch_bounds__(256) void proj4(
    const float* __restrict__ X,
    const float* __restrict__ W0, const float* __restrict__ b0,
    const float* __restrict__ W1, const float* __restrict__ b1,
    const float* __restrict__ W2, const float* __restrict__ b2,
    const float* __restrict__ W3, const float* __restrict__ b3,
    float* __restrict__ out, int n)
{
    __shared__ float Xs[16][64];
    int r0 = blockIdx.x * 16;
    int tid = threadIdx.x;
    for (int i = tid; i < 16 * 64; i += 256) {
        int r = i >> 6, c = i & 63;
        int gr = r0 + r;
        Xs[r][c] = (gr < n) ? X[gr * 64 + c] : 0.f;
    }
    __syncthreads();
    int c = tid & 63;
    int m = tid >> 6;
    const float* W = (m == 0) ? W0 : (m == 1) ? W1 : (m == 2) ? W2 : W3;
    const float* B = (m == 0) ? b0 : (m == 1) ? b1 : (m == 2) ? b2 : b3;
    float bias = B[c];
    float acc[16];
#pragma unroll
    for (int r = 0; r < 16; r++) acc[r] = bias;
    for (int k = 0; k < 64; k++) {
        float w = W[k * 64 + c];
#pragma unroll
        for (int r = 0; r < 16; r++) acc[r] += Xs[r][k] * w;
    }
    for (int r = 0; r < 16; r++) {
        int gr = r0 + r;
        if (gr < n) out[gr * 256 + tid] = acc[r];
    }
}

// ---------- CSR build (once per call, reused by both layers) ----------
__global__ __launch_bounds__(256) void deg_count(const int* __restrict__ ei,
                                                 int* __restrict__ deg) {
    int e = blockIdx.x * 256 + threadIdx.x;
    if (e >= NE) return;
    atomicAdd(&deg[ei[NE + e]], 1);
}

__global__ __launch_bounds__(256) void scan_block(const int* __restrict__ deg,
                                                  int* __restrict__ off,
                                                  int* __restrict__ bsum) {
    __shared__ int buf[256];
    int i = blockIdx.x * 256 + threadIdx.x;
    int v = (i < NN) ? deg[i] : 0;
    buf[threadIdx.x] = v;
    __syncthreads();
    for (int o = 1; o < 256; o <<= 1) {
        int t = (threadIdx.x >= o) ? buf[threadIdx.x - o] : 0;
        __syncthreads();
        buf[threadIdx.x] += t;
        __syncthreads();
    }
    if (i < NN) off[i + 1] = buf[threadIdx.x];
    if (threadIdx.x == 255) bsum[blockIdx.x] = buf[255];
}

__global__ __launch_bounds__(256) void scan_tot(const int* __restrict__ bsum,
                                                int* __restrict__ boff) {
    __shared__ int buf[256];
    int v = (threadIdx.x < NB) ? bsum[threadIdx.x] : 0;
    buf[threadIdx.x] = v;
    __syncthreads();
    for (int o = 1; o < 256; o <<= 1) {
        int t = (threadIdx.x >= o) ? buf[threadIdx.x - o] : 0;
        __syncthreads();
        buf[threadIdx.x] += t;
        __syncthreads();
    }
    boff[threadIdx.x] = (threadIdx.x == 0) ? 0 : buf[threadIdx.x - 1];
}

// also initializes cur[] = final off[] (replaces the d2d memcpy)
__global__ __launch_bounds__(256) void scan_add(int* __restrict__ off,
                                                const int* __restrict__ boff,
                                                int* __restrict__ cur) {
    int i = blockIdx.x * 256 + threadIdx.x;
    if (i < NN) {
        int v = off[i + 1] + boff[blockIdx.x];
        off[i + 1] = v;
        cur[i + 1] = v;
    }
    if (i == 0) { off[0] = 0; cur[0] = 0; }
}

// packed (src, weight) per edge: one 8B store instead of two 4B stores
__global__ __launch_bounds__(256) void csr_fill(const int* __restrict__ ei,
                                                const float* __restrict__ ew,
                                                int* __restrict__ cur,
                                                uint2* __restrict__ ES) {
    int e = blockIdx.x * 256 + threadIdx.x;
    if (e >= NE) return;
    int dst = ei[NE + e];
    int pos = atomicAdd(&cur[dst], 1);
    ES[pos] = make_uint2((unsigned)ei[e], __float_as_uint(ew[e]));
}

// ---------- fused attention: one wave per dst node, 4 edges/iter ----------
// 16 lanes per edge, float4 per lane. TWO-PASS softmax (exact max, then
// Kahan-compensated sums) so the result is invariant to the nondeterministic
// bucket ordering produced by csr_fill's atomic slot assignment.
// logit = (q.k[src] + w*(q.We))/8 ; agg = (Σ a*v[src] + (Σ a*w)*We) / Σ a
__global__ __launch_bounds__(256) void attn_fused(
    const int* __restrict__ off, const uint2* __restrict__ ES,
    const float* __restrict__ We,
    const float* __restrict__ QKVS, float* __restrict__ L,
    float* __restrict__ H, int n)
{
    int wid = blockIdx.x * 4 + (threadIdx.x >> 6);
    if (wid >= n) return;
    int lane = threadIdx.x & 63;
    int g = lane >> 4;       // edge group 0..3
    int c = lane & 15;       // feature-quad index 0..15

    const float4* Q4 = (const float4*)(QKVS + (size_t)wid * 256);
    float4 q4 = Q4[c];
    float4 we4 = ((const float4*)We)[c];

    // qwe = dot(q, We), reduced within the 16-lane group
    float p = q4.x * we4.x + q4.y * we4.y + q4.z * we4.z + q4.w * we4.w;
    p += __shfl_xor(p, 1); p += __shfl_xor(p, 2);
    p += __shfl_xor(p, 4); p += __shfl_xor(p, 8);
    float qwe = p;

    int e0 = off[wid], e1 = off[wid + 1];

    // ---- pass 1: logits -> L, exact max (order-independent) ----
    float m = -INFINITY;
    for (int e = e0 + g; e < e1; e += 4) {
        uint2 ed = ES[e];
        int src = (int)ed.x;
        float w = __uint_as_float(ed.y);
        const float4* R4 = (const float4*)(QKVS + (size_t)src * 256 + 64);
        float4 k4 = R4[c];
        float d = q4.x * k4.x + q4.y * k4.y + q4.z * k4.z + q4.w * k4.w;
        d += __shfl_xor(d, 1); d += __shfl_xor(d, 2);
        d += __shfl_xor(d, 4); d += __shfl_xor(d, 8);
        float logit = (d + w * qwe) * 0.125f;
        if (c == 0) L[e] = logit;
        m = fmaxf(m, logit);
    }
    m = fmaxf(m, __shfl_xor(m, 16));
    m = fmaxf(m, __shfl_xor(m, 32));   // global bucket max, all lanes

    // ---- pass 2: Kahan-compensated accumulation (partition-invariant) ----
    float s = 0.f, cs = 0.f, aw = 0.f, caw = 0.f;
    float4 acc = make_float4(0.f, 0.f, 0.f, 0.f);
    float4 cac = make_float4(0.f, 0.f, 0.f, 0.f);
    for (int e = e0 + g; e < e1; e += 4) {
        uint2 ed = ES[e];
        int src = (int)ed.x;
        float w = __uint_as_float(ed.y);
        float a = expf(L[e] - m);
        const float4* R4 = (const float4*)(QKVS + (size_t)src * 256 + 128);
        float4 v4 = R4[c];
        KAH(s, cs, a);
        KAH(aw, caw, a * w);
        KAH(acc.x, cac.x, a * v4.x);
        KAH(acc.y, cac.y, a * v4.y);
        KAH(acc.z, cac.z, a * v4.z);
        KAH(acc.w, cac.w, a * v4.w);
    }

    // merge the 4 groups' partial sums (fixed shuffle pattern, near-exact partials)
#pragma unroll
    for (int o = 16; o <= 32; o <<= 1) {
        s += __shfl_xor(s, o);
        aw += __shfl_xor(aw, o);
        acc.x += __shfl_xor(acc.x, o);
        acc.y += __shfl_xor(acc.y, o);
        acc.z += __shfl_xor(acc.z, o);
        acc.w += __shfl_xor(acc.w, o);
    }

    if (g == 0) {
        float inv = 1.f / (s + 1e-16f);
        float4 sp4 = Q4[48 + c];   // sproj at cols 192..255
        float4 o4;
        o4.x = fmaxf((acc.x + aw * we4.x) * inv + sp4.x, 0.f);
        o4.y = fmaxf((acc.y + aw * we4.y) * inv + sp4.y, 0.f);
        o4.z = fmaxf((acc.z + aw * we4.z) * inv + sp4.z, 0.f);
        o4.w = fmaxf((acc.w + aw * we4.w) * inv + sp4.w, 0.f);
        ((float4*)(H + (size_t)wid * 64))[c] = o4;
    }
}

// ---------- deterministic mean-pool: one block per group ----------
// batch is sorted: binary-search segment bounds, fixed-order reduction, no atomics.
__global__ __launch_bounds__(256) void pool_kernel(
    const float* __restrict__ H, const int* __restrict__ batch,
    float* __restrict__ pooled, int n)
{
    int gid = blockIdx.x;            // group 0..NG-1
    int wv = threadIdx.x >> 6;
    int lane = threadIdx.x & 63;

    // lower_bound(batch, gid) and lower_bound(batch, gid+1)
    int lo = 0, hi = n;
    while (lo < hi) { int mid = (lo + hi) >> 1; if (batch[mid] < gid) lo = mid + 1; else hi = mid; }
    int lo2 = lo, hi2 = n;
    while (lo2 < hi2) { int mid = (lo2 + hi2) >> 1; if (batch[mid] < gid + 1) lo2 = mid + 1; else hi2 = mid; }
    int cnt = lo2 - lo;

    float acc = 0.f;
    for (int i = lo + wv; i < lo2; i += 4) acc += H[(size_t)i * 64 + lane];

    __shared__ float buf[4][64];
    buf[wv][lane] = acc;
    __syncthreads();
    if (wv == 0) {
        float v = buf[0][lane] + buf[1][lane] + buf[2][lane] + buf[3][lane];
        pooled[gid * 64 + lane] = v / fmaxf((float)cnt, 1.f);
    }
}

__global__ __launch_bounds__(256) void final_kernel(
    const float* __restrict__ pooled,
    const float* __restrict__ Wl, const float* __restrict__ bl,
    float* __restrict__ out)
{
    int t = blockIdx.x * 256 + threadIdx.x;
    if (t >= NG * 2) return;
    int g = t >> 1, c = t & 1;
    float acc = bl[c];
    for (int h = 0; h < 64; h++) acc += pooled[g * 64 + h] * Wl[h * 2 + c];
    out[t] = acc;
}

extern "C" void kernel_launch(void* const* d_in, const int* in_sizes, int n_in,
                              void* d_out, int out_size, void* d_ws, size_t ws_size,
                              hipStream_t stream) {
    const float* x     = (const float*)d_in[0];
    const int*   ei    = (const int*)d_in[1];
    const float* ew    = (const float*)d_in[2];
    const int*   batch = (const int*)d_in[3];
    const float* Wq1 = (const float*)d_in[4];  const float* bq1 = (const float*)d_in[5];
    const float* Wk1 = (const float*)d_in[6];  const float* bk1 = (const float*)d_in[7];
    const float* Wv1 = (const float*)d_in[8];  const float* bv1 = (const float*)d_in[9];
    const float* We1 = (const float*)d_in[10];
    const float* Ws1 = (const float*)d_in[11]; const float* bs1 = (const float*)d_in[12];
    const float* Wq2 = (const float*)d_in[13]; const float* bq2 = (const float*)d_in[14];
    const float* Wk2 = (const float*)d_in[15]; const float* bk2 = (const float*)d_in[16];
    const float* Wv2 = (const float*)d_in[17]; const float* bv2 = (const float*)d_in[18];
    const float* We2 = (const float*)d_in[19];
    const float* Ws2 = (const float*)d_in[20]; const float* bs2 = (const float*)d_in[21];
    const float* Wl  = (const float*)d_in[22]; const float* bl  = (const float*)d_in[23];
    float* out = (float*)d_out;

    // layout: big arrays first (all offsets 16B-aligned)
    char* w = (char*)d_ws;
    float* QKVS = (float*)w; w += (size_t)NN * 256 * 4;   // 51.2 MB
    float* H    = (float*)w; w += (size_t)NN * 64 * 4;    // 12.8 MB
    uint2* ES   = (uint2*)w; w += (size_t)NE * 8;         // 6.4 MB
    float* L    = (float*)w; w += (size_t)NE * 4;         // 3.2 MB
    int*   off  = (int*)w;   w += (size_t)(NN + 4) * 4;
    int*   cur  = (int*)w;   w += (size_t)(NN + 4) * 4;
    int*   deg  = (int*)w;   w += (size_t)(NN + 4) * 4;
    int*   bsum = (int*)w;   w += 256 * 4;
    int*   boff = (int*)w;   w += 256 * 4;
    float* pooled = (float*)w; w += (size_t)NG * 64 * 4;

    dim3 blk(256);
    int gProj = (NN + 15) / 16;
    int gEdge = (NE + 255) / 256;
    int gAttn = (NN + 3) / 4;

    // ---- CSR build (dst-sorted adjacency), shared by both layers ----
    hipMemsetAsync(deg, 0, (size_t)NN * 4, stream);
    deg_count<<<gEdge, blk, 0, stream>>>(ei, deg);
    scan_block<<<NB, blk, 0, stream>>>(deg, off, bsum);
    scan_tot<<<1, blk, 0, stream>>>(bsum, boff);
    scan_add<<<NB, blk, 0, stream>>>(off, boff, cur);
    csr_fill<<<gEdge, blk, 0, stream>>>(ei, ew, cur, ES);

    // ---- layer 1 ----
    proj4<<<gProj, blk, 0, stream>>>(x, Wq1, bq1, Wk1, bk1, Wv1, bv1, Ws1, bs1, QKVS, NN);
    attn_fused<<<gAttn, blk, 0, stream>>>(off, ES, We1, QKVS, L, H, NN);

    // ---- layer 2 ----
    proj4<<<gProj, blk, 0, stream>>>(H, Wq2, bq2, Wk2, bk2, Wv2, bv2, Ws2, bs2, QKVS, NN);
    attn_fused<<<gAttn, blk, 0, stream>>>(off, ES, We2, QKVS, L, H, NN);

    // ---- pooling + classifier ----
    pool_kernel<<<NG, blk, 0, stream>>>(H, batch, pooled, NN);
    final_kernel<<<2, blk, 0, stream>>>(pooled, Wl, bl, out);
}

// Round 7
// 430.898 us; speedup vs baseline: 2.4858x; 1.0141x over previous
//
#include <hip/hip_runtime.h>
#include <math.h>

#define NN 50000
#define NE 800000
#define NG 256
#define NB ((NN + 255) / 256)   // 196 scan blocks

// Fused x@{W0,W1,W2,W3}+b -> out[N][256] (cols 0-63:q, 64-127:k, 128-191:v, 192-255:s)
__global__ __launch_bounds__(256) void proj4(
    const float* __restrict__ X,
    const float* __restrict__ W0, const float* __restrict__ b0,
    const float* __restrict__ W1, const float* __restrict__ b1,
    const float* __restrict__ W2, const float* __restrict__ b2,
    const float* __restrict__ W3, const float* __restrict__ b3,
    float* __restrict__ out, int n)
{
    __shared__ float Xs[16][64];
    int r0 = blockIdx.x * 16;
    int tid = threadIdx.x;
    for (int i = tid; i < 16 * 64; i += 256) {
        int r = i >> 6, c = i & 63;
        int gr = r0 + r;
        Xs[r][c] = (gr < n) ? X[gr * 64 + c] : 0.f;
    }
    __syncthreads();
    int c = tid & 63;
    int m = tid >> 6;
    const float* W = (m == 0) ? W0 : (m == 1) ? W1 : (m == 2) ? W2 : W3;
    const float* B = (m == 0) ? b0 : (m == 1) ? b1 : (m == 2) ? b2 : b3;
    float bias = B[c];
    float acc[16];
#pragma unroll
    for (int r = 0; r < 16; r++) acc[r] = bias;
    for (int k = 0; k < 64; k++) {
        float w = W[k * 64 + c];
#pragma unroll
        for (int r = 0; r < 16; r++) acc[r] += Xs[r][k] * w;
    }
    for (int r = 0; r < 16; r++) {
        int gr = r0 + r;
        if (gr < n) out[gr * 256 + tid] = acc[r];
    }
}

// ---------- CSR build (once per call, reused by both layers) ----------
__global__ __launch_bounds__(256) void deg_count(const int* __restrict__ ei,
                                                 int* __restrict__ deg) {
    int e = blockIdx.x * 256 + threadIdx.x;
    if (e >= NE) return;
    atomicAdd(&deg[ei[NE + e]], 1);
}

__global__ __launch_bounds__(256) void scan_block(const int* __restrict__ deg,
                                                  int* __restrict__ off,
                                                  int* __restrict__ bsum) {
    __shared__ int buf[256];
    int i = blockIdx.x * 256 + threadIdx.x;
    int v = (i < NN) ? deg[i] : 0;
    buf[threadIdx.x] = v;
    __syncthreads();
    for (int o = 1; o < 256; o <<= 1) {
        int t = (threadIdx.x >= o) ? buf[threadIdx.x - o] : 0;
        __syncthreads();
        buf[threadIdx.x] += t;
        __syncthreads();
    }
    if (i < NN) off[i + 1] = buf[threadIdx.x];
    if (threadIdx.x == 255) bsum[blockIdx.x] = buf[255];
}

__global__ __launch_bounds__(256) void scan_tot(const int* __restrict__ bsum,
                                                int* __restrict__ boff) {
    __shared__ int buf[256];
    int v = (threadIdx.x < NB) ? bsum[threadIdx.x] : 0;
    buf[threadIdx.x] = v;
    __syncthreads();
    for (int o = 1; o < 256; o <<= 1) {
        int t = (threadIdx.x >= o) ? buf[threadIdx.x - o] : 0;
        __syncthreads();
        buf[threadIdx.x] += t;
        __syncthreads();
    }
    boff[threadIdx.x] = (threadIdx.x == 0) ? 0 : buf[threadIdx.x - 1];
}

// also initializes cur[] = final off[] (replaces the d2d memcpy)
__global__ __launch_bounds__(256) void scan_add(int* __restrict__ off,
                                                const int* __restrict__ boff,
                                                int* __restrict__ cur) {
    int i = blockIdx.x * 256 + threadIdx.x;
    if (i < NN) {
        int v = off[i + 1] + boff[blockIdx.x];
        off[i + 1] = v;
        cur[i + 1] = v;
    }
    if (i == 0) { off[0] = 0; cur[0] = 0; }
}

// packed (src, weight) per edge: one 8B store instead of two 4B stores
__global__ __launch_bounds__(256) void csr_fill(const int* __restrict__ ei,
                                                const float* __restrict__ ew,
                                                int* __restrict__ cur,
                                                uint2* __restrict__ ES) {
    int e = blockIdx.x * 256 + threadIdx.x;
    if (e >= NE) return;
    int dst = ei[NE + e];
    int pos = atomicAdd(&cur[dst], 1);
    ES[pos] = make_uint2((unsigned)ei[e], __float_as_uint(ew[e]));
}

// ---------- fused attention: one wave per dst node, 4 edges/iter ----------
// 16 lanes per edge, float4 per lane. TWO-PASS softmax: exact bucket max
// (order-invariant), then f64 accumulation (partition jitter ~1e-16, vanishes
// at the f32 convert) -> result invariant to csr_fill's atomic slot ordering.
// __expf is a pure function of (logit, m), both order-invariant -> safe.
// logit = (q.k[src] + w*(q.We))/8 ; agg = (Σ a*v[src] + (Σ a*w)*We) / Σ a
__global__ __launch_bounds__(256) void attn_fused(
    const int* __restrict__ off, const uint2* __restrict__ ES,
    const float* __restrict__ We,
    const float* __restrict__ QKVS, float* __restrict__ L,
    float* __restrict__ H, int n)
{
    int wid = blockIdx.x * 4 + (threadIdx.x >> 6);
    if (wid >= n) return;
    int lane = threadIdx.x & 63;
    int g = lane >> 4;       // edge group 0..3
    int c = lane & 15;       // feature-quad index 0..15

    const float4* Q4 = (const float4*)(QKVS + (size_t)wid * 256);
    float4 q4 = Q4[c];
    float4 we4 = ((const float4*)We)[c];

    // qwe = dot(q, We), reduced within the 16-lane group
    float p = q4.x * we4.x + q4.y * we4.y + q4.z * we4.z + q4.w * we4.w;
    p += __shfl_xor(p, 1); p += __shfl_xor(p, 2);
    p += __shfl_xor(p, 4); p += __shfl_xor(p, 8);
    float qwe = p;

    int e0 = off[wid], e1 = off[wid + 1];

    // ---- pass 1: logits -> L, exact max (order-independent) ----
    float m = -INFINITY;
    for (int e = e0 + g; e < e1; e += 4) {
        uint2 ed = ES[e];
        int src = (int)ed.x;
        float w = __uint_as_float(ed.y);
        const float4* R4 = (const float4*)(QKVS + (size_t)src * 256 + 64);
        float4 k4 = R4[c];
        float d = q4.x * k4.x + q4.y * k4.y + q4.z * k4.z + q4.w * k4.w;
        d += __shfl_xor(d, 1); d += __shfl_xor(d, 2);
        d += __shfl_xor(d, 4); d += __shfl_xor(d, 8);
        float logit = (d + w * qwe) * 0.125f;
        if (c == 0) L[e] = logit;
        m = fmaxf(m, logit);
    }
    m = fmaxf(m, __shfl_xor(m, 16));
    m = fmaxf(m, __shfl_xor(m, 32));   // global bucket max, all lanes

    // ---- pass 2: f64 accumulation (order-invariant to fp32 precision) ----
    double s = 0.0, aw = 0.0;
    double ax = 0.0, ay = 0.0, az = 0.0, az2 = 0.0;
    for (int e = e0 + g; e < e1; e += 4) {
        uint2 ed = ES[e];
        int src = (int)ed.x;
        float w = __uint_as_float(ed.y);
        float a = __expf(L[e] - m);
        const float4* R4 = (const float4*)(QKVS + (size_t)src * 256 + 128);
        float4 v4 = R4[c];
        double da = (double)a;
        s += da;
        aw = fma(da, (double)w, aw);
        ax = fma(da, (double)v4.x, ax);
        ay = fma(da, (double)v4.y, ay);
        az = fma(da, (double)v4.z, az);
        az2 = fma(da, (double)v4.w, az2);
    }

    // fixed-pattern merge of the 4 groups' partials (deterministic)
    float fs = (float)s, faw = (float)aw;
    float fx = (float)ax, fy = (float)ay, fz = (float)az, fw = (float)az2;
#pragma unroll
    for (int o = 16; o <= 32; o <<= 1) {
        fs += __shfl_xor(fs, o);
        faw += __shfl_xor(faw, o);
        fx += __shfl_xor(fx, o);
        fy += __shfl_xor(fy, o);
        fz += __shfl_xor(fz, o);
        fw += __shfl_xor(fw, o);
    }

    if (g == 0) {
        float inv = 1.f / (fs + 1e-16f);
        float4 sp4 = Q4[48 + c];   // sproj at cols 192..255
        float4 o4;
        o4.x = fmaxf((fx + faw * we4.x) * inv + sp4.x, 0.f);
        o4.y = fmaxf((fy + faw * we4.y) * inv + sp4.y, 0.f);
        o4.z = fmaxf((fz + faw * we4.z) * inv + sp4.z, 0.f);
        o4.w = fmaxf((fw + faw * we4.w) * inv + sp4.w, 0.f);
        ((float4*)(H + (size_t)wid * 64))[c] = o4;
    }
}

// ---------- deterministic mean-pool + classifier: one block per group ----------
// batch is sorted: binary-search segment bounds, fixed-order reduction, then
// the 2-class linear head, all in one kernel (no atomics).
__global__ __launch_bounds__(256) void pool_final(
    const float* __restrict__ H, const int* __restrict__ batch,
    const float* __restrict__ Wl, const float* __restrict__ bl,
    float* __restrict__ out, int n)
{
    int gid = blockIdx.x;            // group 0..NG-1
    int wv = threadIdx.x >> 6;
    int lane = threadIdx.x & 63;

    int lo = 0, hi = n;
    while (lo < hi) { int mid = (lo + hi) >> 1; if (batch[mid] < gid) lo = mid + 1; else hi = mid; }
    int lo2 = lo, hi2 = n;
    while (lo2 < hi2) { int mid = (lo2 + hi2) >> 1; if (batch[mid] < gid + 1) lo2 = mid + 1; else hi2 = mid; }
    int cnt = lo2 - lo;

    float acc = 0.f;
    for (int i = lo + wv; i < lo2; i += 4) acc += H[(size_t)i * 64 + lane];

    __shared__ float buf[4][64];
    __shared__ float pl[64];
    buf[wv][lane] = acc;
    __syncthreads();
    if (wv == 0) {
        float v = buf[0][lane] + buf[1][lane] + buf[2][lane] + buf[3][lane];
        pl[lane] = v / fmaxf((float)cnt, 1.f);
    }
    __syncthreads();
    if (wv == 0) {
        // 2-class head: two fixed-order shuffle reductions over 64 lanes
        float t0 = pl[lane] * Wl[lane * 2 + 0];
        float t1 = pl[lane] * Wl[lane * 2 + 1];
#pragma unroll
        for (int o = 1; o < 64; o <<= 1) {
            t0 += __shfl_xor(t0, o);
            t1 += __shfl_xor(t1, o);
        }
        if (lane == 0) {
            out[gid * 2 + 0] = t0 + bl[0];
            out[gid * 2 + 1] = t1 + bl[1];
        }
    }
}

extern "C" void kernel_launch(void* const* d_in, const int* in_sizes, int n_in,
                              void* d_out, int out_size, void* d_ws, size_t ws_size,
                              hipStream_t stream) {
    const float* x     = (const float*)d_in[0];
    const int*   ei    = (const int*)d_in[1];
    const float* ew    = (const float*)d_in[2];
    const int*   batch = (const int*)d_in[3];
    const float* Wq1 = (const float*)d_in[4];  const float* bq1 = (const float*)d_in[5];
    const float* Wk1 = (const float*)d_in[6];  const float* bk1 = (const float*)d_in[7];
    const float* Wv1 = (const float*)d_in[8];  const float* bv1 = (const float*)d_in[9];
    const float* We1 = (const float*)d_in[10];
    const float* Ws1 = (const float*)d_in[11]; const float* bs1 = (const float*)d_in[12];
    const float* Wq2 = (const float*)d_in[13]; const float* bq2 = (const float*)d_in[14];
    const float* Wk2 = (const float*)d_in[15]; const float* bk2 = (const float*)d_in[16];
    const float* Wv2 = (const float*)d_in[17]; const float* bv2 = (const float*)d_in[18];
    const float* We2 = (const float*)d_in[19];
    const float* Ws2 = (const float*)d_in[20]; const float* bs2 = (const float*)d_in[21];
    const float* Wl  = (const float*)d_in[22]; const float* bl  = (const float*)d_in[23];
    float* out = (float*)d_out;

    // layout: big arrays first (all offsets 16B-aligned)
    char* w = (char*)d_ws;
    float* QKVS = (float*)w; w += (size_t)NN * 256 * 4;   // 51.2 MB
    float* H    = (float*)w; w += (size_t)NN * 64 * 4;    // 12.8 MB
    uint2* ES   = (uint2*)w; w += (size_t)NE * 8;         // 6.4 MB
    float* L    = (float*)w; w += (size_t)NE * 4;         // 3.2 MB
    int*   off  = (int*)w;   w += (size_t)(NN + 4) * 4;
    int*   cur  = (int*)w;   w += (size_t)(NN + 4) * 4;
    int*   deg  = (int*)w;   w += (size_t)(NN + 4) * 4;
    int*   bsum = (int*)w;   w += 256 * 4;
    int*   boff = (int*)w;   w += 256 * 4;

    dim3 blk(256);
    int gProj = (NN + 15) / 16;
    int gEdge = (NE + 255) / 256;
    int gAttn = (NN + 3) / 4;

    // ---- CSR build (dst-sorted adjacency), shared by both layers ----
    hipMemsetAsync(deg, 0, (size_t)NN * 4, stream);
    deg_count<<<gEdge, blk, 0, stream>>>(ei, deg);
    scan_block<<<NB, blk, 0, stream>>>(deg, off, bsum);
    scan_tot<<<1, blk, 0, stream>>>(bsum, boff);
    scan_add<<<NB, blk, 0, stream>>>(off, boff, cur);
    csr_fill<<<gEdge, blk, 0, stream>>>(ei, ew, cur, ES);

    // ---- layer 1 ----
    proj4<<<gProj, blk, 0, stream>>>(x, Wq1, bq1, Wk1, bk1, Wv1, bv1, Ws1, bs1, QKVS, NN);
    attn_fused<<<gAttn, blk, 0, stream>>>(off, ES, We1, QKVS, L, H, NN);

    // ---- layer 2 ----
    proj4<<<gProj, blk, 0, stream>>>(H, Wq2, bq2, Wk2, bk2, Wv2, bv2, Ws2, bs2, QKVS, NN);
    attn_fused<<<gAttn, blk, 0, stream>>>(off, ES, We2, QKVS, L, H, NN);

    // ---- pooling + classifier (fused) ----
    pool_final<<<NG, blk, 0, stream>>>(H, batch, Wl, bl, out, NN);
}